// Round 4
// baseline (6152.553 us; speedup 1.0000x reference)
//
#include <hip/hip_runtime.h>
#include <hip/hip_bf16.h>
#include <cstdint>

#define DEV __device__ __forceinline__

// Exact per-op-rounded squared distance, matching numpy's ((dx^2+dy^2)+dz^2)
// with no FMA contraction. All index decisions (FPS/ball/kNN) depend on this
// being bit-identical to the f32 reference.
DEV float sqdist(float ax, float ay, float az, float bx, float by, float bz) {
    float dx = __fsub_rn(ax, bx), dy = __fsub_rn(ay, by), dz = __fsub_rn(az, bz);
    return __fadd_rn(__fadd_rn(__fmul_rn(dx, dx), __fmul_rn(dy, dy)), __fmul_rn(dz, dz));
}

DEV unsigned short f2bf(float f) {  // RNE f32 -> bf16 (ws feature storage only)
    unsigned int u = __float_as_uint(f);
    u += 0x7fffu + ((u >> 16) & 1u);
    return (unsigned short)(u >> 16);
}

DEV float bf2f(unsigned short u) { return __uint_as_float(((unsigned int)u) << 16); }

// Output offsets (f32 elements) in return order.
enum : int {
    O_X1 = 0, O_X2 = 12288, O_X3 = 15360,
    O_I1 = 16128, O_I2 = 20224, O_I3 = 21248,
    O_U0 = 21504, O_U1 = 545792, O_U2 = 807936, O_U3 = 939008
};

// ---------------------------------------------------------------- init ------
// xyz[b][n][3] = pc[b][c][n]; f0[b][n][32] = bf16(relu(W0 * feat + b0))
__global__ __launch_bounds__(256) void k_init(const float* __restrict__ pc,
                                              const float* __restrict__ feat,
                                              const float* __restrict__ w0,
                                              const float* __restrict__ b0,
                                              float* __restrict__ xyz,
                                              unsigned short* __restrict__ f0) {
    const int N = 8192;
    int i = blockIdx.x * blockDim.x + threadIdx.x;
    if (i >= 2 * N) return;
    int b = i / N, n = i % N;
    float fx0 = feat[(b * 3 + 0) * N + n];
    float fx1 = feat[(b * 3 + 1) * N + n];
    float fx2 = feat[(b * 3 + 2) * N + n];
    xyz[i * 3 + 0] = pc[(b * 3 + 0) * N + n];
    xyz[i * 3 + 1] = pc[(b * 3 + 1) * N + n];
    xyz[i * 3 + 2] = pc[(b * 3 + 2) * N + n];
#pragma unroll
    for (int o = 0; o < 32; o++) {
        float acc = b0[o];
        acc = fmaf(w0[o * 3 + 0], fx0, acc);
        acc = fmaf(w0[o * 3 + 1], fx1, acc);
        acc = fmaf(w0[o * 3 + 2], fx2, acc);
        f0[(size_t)i * 32 + o] = f2bf(fmaxf(acc, 0.f));
    }
}

// ----------------------------------------------------------------- FPS ------
template <int N, int M, int T>
__global__ __launch_bounds__(T) void k_fps(const float* __restrict__ xyz,
                                           int* __restrict__ idx_out) {
    constexpr int P = N / T;
    constexpr int W = T / 64;
    constexpr bool LDSXYZ = (3 * N * 4) <= 49152;
    int b = blockIdx.x;
    const float* X = xyz + (size_t)b * N * 3;
    int t = threadIdx.x;
    __shared__ float sdv[W];
    __shared__ int sdi[W];
    __shared__ float sx[LDSXYZ ? N : 1];
    __shared__ float sy[LDSXYZ ? N : 1];
    __shared__ float sz[LDSXYZ ? N : 1];
    float px[P], py[P], pz[P], dmin[P];
    float c0x = X[0], c0y = X[1], c0z = X[2];
#pragma unroll
    for (int i = 0; i < P; i++) {
        int p = i * T + t;
        px[i] = X[p * 3 + 0];
        py[i] = X[p * 3 + 1];
        pz[i] = X[p * 3 + 2];
        if constexpr (LDSXYZ) { sx[p] = px[i]; sy[p] = py[i]; sz[p] = pz[i]; }
        dmin[i] = sqdist(px[i], py[i], pz[i], c0x, c0y, c0z);
    }
    if (t == 0) idx_out[b * M] = 0;
    for (int j = 1; j < M; j++) {
        // lane-local first-max (strict > keeps smallest index among ties)
        float bv = -1.0f;
        int bi = 0;
#pragma unroll
        for (int i = 0; i < P; i++)
            if (dmin[i] > bv) { bv = dmin[i]; bi = i * T + t; }
        // wave butterfly: lexicographic (max value, min index)
#pragma unroll
        for (int m = 1; m < 64; m <<= 1) {
            float ov = __shfl_xor(bv, m, 64);
            int oi = __shfl_xor(bi, m, 64);
            if (ov > bv || (ov == bv && oi < bi)) { bv = ov; bi = oi; }
        }
        if ((t & 63) == 0) { sdv[t >> 6] = bv; sdi[t >> 6] = bi; }
        __syncthreads();
        bv = sdv[0]; bi = sdi[0];
#pragma unroll
        for (int w = 1; w < W; w++) {
            float ov = sdv[w]; int oi = sdi[w];
            if (ov > bv || (ov == bv && oi < bi)) { bv = ov; bi = oi; }
        }
        if (t == 0) idx_out[b * M + j] = bi;
        float cx, cy, cz;
        if constexpr (LDSXYZ) {
            cx = sx[bi]; cy = sy[bi]; cz = sz[bi];
        } else {
            cx = X[bi * 3 + 0]; cy = X[bi * 3 + 1]; cz = X[bi * 3 + 2];
        }
#pragma unroll
        for (int i = 0; i < P; i++)
            dmin[i] = fminf(dmin[i], sqdist(px[i], py[i], pz[i], cx, cy, cz));
        __syncthreads();
    }
}

// -------------------------------------------------------------- gather ------
__global__ __launch_bounds__(256) void k_gather(const float* __restrict__ xyz_src,
                                                const int* __restrict__ idx,
                                                float* __restrict__ xyz_dst,
                                                int NS, int M) {
    int i = blockIdx.x * blockDim.x + threadIdx.x;
    if (i >= 2 * M) return;
    int b = i / M;
    int id = idx[i] & (NS - 1);
    xyz_dst[i * 3 + 0] = xyz_src[((size_t)b * NS + id) * 3 + 0];
    xyz_dst[i * 3 + 1] = xyz_src[((size_t)b * NS + id) * 3 + 1];
    xyz_dst[i * 3 + 2] = xyz_src[((size_t)b * NS + id) * 3 + 2];
}

// ------------------------------------------------------------- SetConv ------
// One block (128 thr) per center. Ball query (wave 0, ballot) -> stage
// h=[dxyz, feat(bf16->f32)] in LDS -> mlp1 -> mlp2 + maxpool -> bf16 fout(ws).
template <int NS, int CF, int CMID, int COUT>
__global__ __launch_bounds__(128) void k_setconv(
    const float* __restrict__ X, const unsigned short* __restrict__ F,
    const float* __restrict__ C, const float* __restrict__ w1,
    const float* __restrict__ b1, const float* __restrict__ w2,
    const float* __restrict__ b2, unsigned short* __restrict__ fout,
    float r2, int M) {
    constexpr int CIN = 3 + CF;
    constexpr int K = 16;
    constexpr int M8 = CMID / 8;
    constexpr int O8 = COUT / 8;
    int q = blockIdx.x, b = blockIdx.y;
    int blk = b * M + q;
    const float* Xb = X + (size_t)b * NS * 3;
    const unsigned short* Fb = F + (size_t)b * NS * CF;
    int tid = threadIdx.x;
    __shared__ int s_n[K];
    __shared__ int s_cnt;
    __shared__ float s_h[K][CIN];
    __shared__ float s_mid[K][CMID];
    __shared__ float s_pool[2][COUT];
    float cx = C[(size_t)blk * 3 + 0], cy = C[(size_t)blk * 3 + 1], cz = C[(size_t)blk * 3 + 2];
    if (tid < 64) {
        int lane = tid;
        int cnt = 0;
        for (int base = 0; base < NS; base += 64) {
            int p = base + lane;
            float d2 = sqdist(Xb[p * 3], Xb[p * 3 + 1], Xb[p * 3 + 2], cx, cy, cz);
            bool in = (d2 <= r2);
            unsigned long long msk = __ballot(in);
            if (in) {
                int pos = cnt + __popcll(msk & ((1ull << lane) - 1ull));
                if (pos < K) s_n[pos] = p;
            }
            cnt += __popcll(msk);
            if (cnt >= K) break;
        }
        if (lane == 0) s_cnt = cnt < K ? cnt : K;
    }
    __syncthreads();
    int cnt = s_cnt;
    if (tid >= cnt && tid < K) s_n[tid] = s_n[0];  // pad (center itself always hits)
    __syncthreads();
    for (int tIdx = tid; tIdx < K * CIN; tIdx += 128) {
        int n = tIdx / CIN, c = tIdx % CIN;
        int gi = s_n[n];
        float v;
        if (c < 3) v = __fsub_rn(Xb[gi * 3 + c], (c == 0 ? cx : (c == 1 ? cy : cz)));
        else v = bf2f(Fb[(size_t)gi * CF + (c - 3)]);
        s_h[n][c] = v;
    }
    __syncthreads();
    int n = tid >> 3, sub = tid & 7;
#pragma unroll
    for (int j = 0; j < M8; j++) {
        int m = sub * M8 + j;
        float acc = b1[m];
#pragma unroll 4
        for (int c = 0; c < CIN; c++) acc = fmaf(w1[m * CIN + c], s_h[n][c], acc);
        s_mid[n][m] = fmaxf(acc, 0.f);
    }
    __syncthreads();
    float vals[O8];
#pragma unroll
    for (int j = 0; j < O8; j++) {
        int o = sub * O8 + j;
        float acc = b2[o];
#pragma unroll 4
        for (int c = 0; c < CMID; c++) acc = fmaf(w2[o * CMID + c], s_mid[n][c], acc);
        vals[j] = fmaxf(acc, 0.f);
    }
#pragma unroll
    for (int j = 0; j < O8; j++) {
        vals[j] = fmaxf(vals[j], __shfl_xor(vals[j], 8, 64));
        vals[j] = fmaxf(vals[j], __shfl_xor(vals[j], 16, 64));
        vals[j] = fmaxf(vals[j], __shfl_xor(vals[j], 32, 64));
    }
    int lw = tid & 63, wv = tid >> 6;
    if (lw < 8) {
#pragma unroll
        for (int j = 0; j < O8; j++) s_pool[wv][lw * O8 + j] = vals[j];
    }
    __syncthreads();
    if (tid < 8) {
#pragma unroll
        for (int j = 0; j < O8; j++) {
            int o = tid * O8 + j;
            fout[(size_t)blk * COUT + o] = f2bf(fmaxf(s_pool[0][o], s_pool[1][o]));
        }
    }
}

// ------------------------------------------------------------ SetUpConv -----
// One wave per dense point. kNN k=8 -> MLP -> maxpool -> fuse -> write f32
// DIRECTLY into the final out U-region ([b][COUT][ND] layout). SF source:
// TRANS=true reads f32 from an out U-region ([b][CS][S]); false reads bf16
// from ws ([b][S][CS]). DF is ws bf16 [b][ND][CD].
template <int S, int CS, int CMID, int CD, int COUT, bool TRANS>
__global__ __launch_bounds__(64) void k_upconv(
    const float* __restrict__ SX, const float* __restrict__ DX,
    const void* __restrict__ SFv, const unsigned short* __restrict__ DF,
    const float* __restrict__ w1, const float* __restrict__ b1,
    const float* __restrict__ w2, const float* __restrict__ b2,
    float* __restrict__ out, int o_off, int ND) {
    constexpr int K = 8;
    constexpr int CIN = 3 + CS;
    constexpr int CIN2 = CMID + CD;
    constexpr int M8 = CMID / 8;
    int q = blockIdx.x, b = blockIdx.y;
    int blk = b * ND + q;
    int lane = threadIdx.x;
    const float* SXb = SX + (size_t)b * S * 3;
    float qx = DX[(size_t)blk * 3], qy = DX[(size_t)blk * 3 + 1], qz = DX[(size_t)blk * 3 + 2];
    __shared__ int s_k[K];
    __shared__ float s_h[K][CIN];
    __shared__ float s_in2[CIN2];
    float bd[K];
    int bi[K];
#pragma unroll
    for (int i = 0; i < K; i++) { bd[i] = 3.0e38f; bi[i] = 0x7fffffff; }
    for (int p = lane; p < S; p += 64) {
        float d2 = sqdist(SXb[p * 3], SXb[p * 3 + 1], SXb[p * 3 + 2], qx, qy, qz);
        if (d2 < bd[K - 1] || (d2 == bd[K - 1] && p < bi[K - 1])) {
            bd[K - 1] = d2; bi[K - 1] = p;
#pragma unroll
            for (int j = K - 1; j > 0; j--) {
                bool sw = (bd[j] < bd[j - 1]) || (bd[j] == bd[j - 1] && bi[j] < bi[j - 1]);
                if (sw) {
                    float tv = bd[j]; bd[j] = bd[j - 1]; bd[j - 1] = tv;
                    int ti = bi[j]; bi[j] = bi[j - 1]; bi[j - 1] = ti;
                }
            }
        }
    }
    for (int r = 0; r < K; r++) {
        float vv = bd[0]; int vi = bi[0];
#pragma unroll
        for (int m = 1; m < 64; m <<= 1) {
            float ov = __shfl_xor(vv, m, 64);
            int oi = __shfl_xor(vi, m, 64);
            if (ov < vv || (ov == vv && oi < vi)) { vv = ov; vi = oi; }
        }
        if (lane == 0) s_k[r] = vi;
        if (vi == bi[0]) {
#pragma unroll
            for (int j = 0; j < K - 1; j++) { bd[j] = bd[j + 1]; bi[j] = bi[j + 1]; }
            bd[K - 1] = 3.0e38f; bi[K - 1] = 0x7fffffff;
        }
    }
    __syncthreads();
    for (int tIdx = lane; tIdx < K * CIN; tIdx += 64) {
        int n = tIdx / CIN, c = tIdx % CIN;
        int gi = s_k[n];
        float v;
        if (c < 3) v = __fsub_rn(SXb[gi * 3 + c], (c == 0 ? qx : (c == 1 ? qy : qz)));
        else if (TRANS) v = ((const float*)SFv)[((size_t)b * CS + (c - 3)) * S + gi];
        else v = bf2f(((const unsigned short*)SFv)[((size_t)b * S + gi) * CS + (c - 3)]);
        s_h[n][c] = v;
    }
    for (int c = lane; c < CD; c += 64) s_in2[CMID + c] = bf2f(DF[(size_t)blk * CD + c]);
    __syncthreads();
    int n = lane >> 3, sub = lane & 7;
    float vals[M8];
#pragma unroll
    for (int j = 0; j < M8; j++) {
        int m = sub * M8 + j;
        float acc = b1[m];
#pragma unroll 4
        for (int c = 0; c < CIN; c++) acc = fmaf(w1[m * CIN + c], s_h[n][c], acc);
        vals[j] = fmaxf(acc, 0.f);
    }
#pragma unroll
    for (int j = 0; j < M8; j++) {
        vals[j] = fmaxf(vals[j], __shfl_xor(vals[j], 8, 64));
        vals[j] = fmaxf(vals[j], __shfl_xor(vals[j], 16, 64));
        vals[j] = fmaxf(vals[j], __shfl_xor(vals[j], 32, 64));
    }
    if (lane < 8) {
#pragma unroll
        for (int j = 0; j < M8; j++) s_in2[lane * M8 + j] = vals[j];
    }
    __syncthreads();
    for (int o = lane; o < COUT; o += 64) {
        float acc = b2[o];
#pragma unroll 4
        for (int c = 0; c < CIN2; c++) acc = fmaf(w2[o * CIN2 + c], s_in2[c], acc);
        out[o_off + ((size_t)b * COUT + o) * ND + q] = fmaxf(acc, 0.f);
    }
}

// ------------------------------------------------------------- finalize -----
// Writes x1/x2/x3 ([B,3,M] f32, exact coords) and i1/i2/i3 (f32 of int idx).
__global__ __launch_bounds__(256) void k_finalize(
    const float* __restrict__ xyz1, const float* __restrict__ xyz2,
    const float* __restrict__ xyz3, const int* __restrict__ idx1,
    const int* __restrict__ idx2, const int* __restrict__ idx3,
    float* __restrict__ out) {
    int i = blockIdx.x * blockDim.x + threadIdx.x;
    const float* xs;
    const int* is;
    int M, ox, oi, j;
    if (i < 4096) { xs = xyz1; is = idx1; M = 2048; ox = O_X1; oi = O_I1; j = i; }
    else if (i < 5120) { xs = xyz2; is = idx2; M = 512; ox = O_X2; oi = O_I2; j = i - 4096; }
    else if (i < 5376) { xs = xyz3; is = idx3; M = 128; ox = O_X3; oi = O_I3; j = i - 5120; }
    else return;
    int b = j / M, m = j % M;
    out[ox + (b * 3 + 0) * M + m] = xs[j * 3 + 0];
    out[ox + (b * 3 + 1) * M + m] = xs[j * 3 + 1];
    out[ox + (b * 3 + 2) * M + m] = xs[j * 3 + 2];
    out[oi + j] = (float)is[j];
}

// ---------------------------------------------------------------- launch ----
extern "C" void kernel_launch(void* const* d_in, const int* in_sizes, int n_in,
                              void* d_out, int out_size, void* d_ws, size_t ws_size,
                              hipStream_t stream) {
    const float* pc = (const float*)d_in[0];
    const float* feat = (const float*)d_in[1];
    const float* w0 = (const float*)d_in[2];
    const float* b0v = (const float*)d_in[3];
    const float* sc1w1 = (const float*)d_in[4];  const float* sc1b1 = (const float*)d_in[5];
    const float* sc1w2 = (const float*)d_in[6];  const float* sc1b2 = (const float*)d_in[7];
    const float* sc2w1 = (const float*)d_in[8];  const float* sc2b1 = (const float*)d_in[9];
    const float* sc2w2 = (const float*)d_in[10]; const float* sc2b2 = (const float*)d_in[11];
    const float* sc3w1 = (const float*)d_in[12]; const float* sc3b1 = (const float*)d_in[13];
    const float* sc3w2 = (const float*)d_in[14]; const float* sc3b2 = (const float*)d_in[15];
    const float* sc4w1 = (const float*)d_in[16]; const float* sc4b1 = (const float*)d_in[17];
    const float* sc4w2 = (const float*)d_in[18]; const float* sc4b2 = (const float*)d_in[19];
    const float* up4w1 = (const float*)d_in[20]; const float* up4b1 = (const float*)d_in[21];
    const float* up4w2 = (const float*)d_in[22]; const float* up4b2 = (const float*)d_in[23];
    const float* up3w1 = (const float*)d_in[24]; const float* up3b1 = (const float*)d_in[25];
    const float* up3w2 = (const float*)d_in[26]; const float* up3b2 = (const float*)d_in[27];
    const float* up2w1 = (const float*)d_in[28]; const float* up2b1 = (const float*)d_in[29];
    const float* up2w2 = (const float*)d_in[30]; const float* up2b2 = (const float*)d_in[31];
    const float* up1w1 = (const float*)d_in[32]; const float* up1b1 = (const float*)d_in[33];
    const float* up1w2 = (const float*)d_in[34]; const float* up1b2 = (const float*)d_in[35];
    float* out = (float*)d_out;

    char* ws = (char*)d_ws;
    size_t off = 0;
    auto A = [&](size_t bytes) -> char* {
        char* p = ws + off;
        off += (bytes + 255) & ~(size_t)255;
        return p;
    };
    float* xyz  = (float*)A((size_t)2 * 8192 * 3 * 4);
    int* idx1   = (int*)A((size_t)2 * 2048 * 4);
    int* idx2   = (int*)A((size_t)2 * 512 * 4);
    int* idx3   = (int*)A((size_t)2 * 128 * 4);
    int* idx4   = (int*)A((size_t)2 * 64 * 4);
    float* xyz1 = (float*)A((size_t)2 * 2048 * 3 * 4);
    float* xyz2 = (float*)A((size_t)2 * 512 * 3 * 4);
    float* xyz3 = (float*)A((size_t)2 * 128 * 3 * 4);
    float* xyz4 = (float*)A((size_t)2 * 64 * 3 * 4);
    unsigned short* f0 = (unsigned short*)A((size_t)2 * 8192 * 32 * 2);
    unsigned short* f1 = (unsigned short*)A((size_t)2 * 2048 * 64 * 2);
    unsigned short* f2 = (unsigned short*)A((size_t)2 * 512 * 128 * 2);
    unsigned short* f3 = (unsigned short*)A((size_t)2 * 128 * 192 * 2);
    unsigned short* f4 = (unsigned short*)A((size_t)2 * 64 * 192 * 2);

    k_init<<<(2 * 8192 + 255) / 256, 256, 0, stream>>>(pc, feat, w0, b0v, xyz, f0);

    // ---- down path (ws only)
    k_fps<8192, 2048, 512><<<2, 512, 0, stream>>>(xyz, idx1);
    k_gather<<<16, 256, 0, stream>>>(xyz, idx1, xyz1, 8192, 2048);
    k_setconv<8192, 32, 32, 64><<<dim3(2048, 2), 128, 0, stream>>>(
        xyz, f0, xyz1, sc1w1, sc1b1, sc1w2, sc1b2, f1, 0.25f, 2048);

    k_fps<2048, 512, 256><<<2, 256, 0, stream>>>(xyz1, idx2);
    k_gather<<<4, 256, 0, stream>>>(xyz1, idx2, xyz2, 2048, 512);
    k_setconv<2048, 64, 64, 128><<<dim3(512, 2), 128, 0, stream>>>(
        xyz1, f1, xyz2, sc2w1, sc2b1, sc2w2, sc2b2, f2, 1.0f, 512);

    k_fps<512, 128, 256><<<2, 256, 0, stream>>>(xyz2, idx3);
    k_gather<<<1, 256, 0, stream>>>(xyz2, idx3, xyz3, 512, 128);
    k_setconv<512, 128, 128, 192><<<dim3(128, 2), 128, 0, stream>>>(
        xyz2, f2, xyz3, sc3w1, sc3b1, sc3w2, sc3b2, f3, 4.0f, 128);

    k_fps<128, 64, 128><<<2, 128, 0, stream>>>(xyz3, idx4);
    k_gather<<<1, 128, 0, stream>>>(xyz3, idx4, xyz4, 128, 64);
    k_setconv<128, 192, 192, 192><<<dim3(64, 2), 128, 0, stream>>>(
        xyz3, f3, xyz4, sc4w1, sc4b1, sc4w2, sc4b2, f4, 16.0f, 64);

    // ---- up path: u-features live ONLY in their final out regions (f32)
    k_upconv<64, 192, 192, 192, 192, false><<<dim3(128, 2), 64, 0, stream>>>(
        xyz4, xyz3, f4, f3, up4w1, up4b1, up4w2, up4b2, out, O_U3, 128);
    k_upconv<128, 192, 128, 128, 128, true><<<dim3(512, 2), 64, 0, stream>>>(
        xyz3, xyz2, out + O_U3, f2, up3w1, up3b1, up3w2, up3b2, out, O_U2, 512);
    k_upconv<512, 128, 64, 64, 64, true><<<dim3(2048, 2), 64, 0, stream>>>(
        xyz2, xyz1, out + O_U2, f1, up2w1, up2b1, up2w2, up2b2, out, O_U1, 2048);
    k_upconv<2048, 64, 32, 32, 32, true><<<dim3(8192, 2), 64, 0, stream>>>(
        xyz1, xyz, out + O_U1, f0, up1w1, up1b1, up1w2, up1b2, out, O_U0, 8192);

    // ---- x/i outputs written last
    k_finalize<<<(5376 + 255) / 256, 256, 0, stream>>>(
        xyz1, xyz2, xyz3, idx1, idx2, idx3, out);
}

// Round 5
// 5016.516 us; speedup vs baseline: 1.2265x; 1.2265x over previous
//
#include <hip/hip_runtime.h>
#include <hip/hip_bf16.h>
#include <cstdint>

#define DEV __device__ __forceinline__

// Exact per-op-rounded squared distance, matching numpy's ((dx^2+dy^2)+dz^2)
// with no FMA contraction. All index decisions (FPS/ball/kNN) depend on this
// being bit-identical to the f32 reference.
DEV float sqdist(float ax, float ay, float az, float bx, float by, float bz) {
    float dx = __fsub_rn(ax, bx), dy = __fsub_rn(ay, by), dz = __fsub_rn(az, bz);
    return __fadd_rn(__fadd_rn(__fmul_rn(dx, dx), __fmul_rn(dy, dy)), __fmul_rn(dz, dz));
}

DEV unsigned short f2bf(float f) {  // RNE f32 -> bf16 (ws feature storage only)
    unsigned int u = __float_as_uint(f);
    u += 0x7fffu + ((u >> 16) & 1u);
    return (unsigned short)(u >> 16);
}

DEV float bf2f(unsigned short u) { return __uint_as_float(((unsigned int)u) << 16); }

// Output offsets (f32 elements) in return order.
enum : int {
    O_X1 = 0, O_X2 = 12288, O_X3 = 15360,
    O_I1 = 16128, O_I2 = 20224, O_I3 = 21248,
    O_U0 = 21504, O_U1 = 545792, O_U2 = 807936, O_U3 = 939008
};

// ---------------------------------------------------------------- init ------
__global__ __launch_bounds__(256) void k_init(const float* __restrict__ pc,
                                              const float* __restrict__ feat,
                                              const float* __restrict__ w0,
                                              const float* __restrict__ b0,
                                              float* __restrict__ xyz,
                                              unsigned short* __restrict__ f0) {
    const int N = 8192;
    int i = blockIdx.x * blockDim.x + threadIdx.x;
    if (i >= 2 * N) return;
    int b = i / N, n = i % N;
    float fx0 = feat[(b * 3 + 0) * N + n];
    float fx1 = feat[(b * 3 + 1) * N + n];
    float fx2 = feat[(b * 3 + 2) * N + n];
    xyz[i * 3 + 0] = pc[(b * 3 + 0) * N + n];
    xyz[i * 3 + 1] = pc[(b * 3 + 1) * N + n];
    xyz[i * 3 + 2] = pc[(b * 3 + 2) * N + n];
#pragma unroll
    for (int o = 0; o < 32; o++) {
        float acc = b0[o];
        acc = fmaf(w0[o * 3 + 0], fx0, acc);
        acc = fmaf(w0[o * 3 + 1], fx1, acc);
        acc = fmaf(w0[o * 3 + 2], fx2, acc);
        f0[(size_t)i * 32 + o] = f2bf(fmaxf(acc, 0.f));
    }
}

// ----------------------------------------------------------------- FPS ------
// One block per batch, points + dmin in REGISTERS (launch_bounds(T,2) caps
// VGPR at 256 -> no scratch spill for P<=16).
// Per iteration (ONE barrier):
//   - packed u64 key (dist_bits<<32 | ~idx): butterfly max == (max d, min idx)
//   - owner lane writes winner COORDS to double-buffered LDS slot (no global
//     center re-fetch on the critical path)
//   - all threads serial-reduce W wave slots, update dmin + track next best
//     (argmax fused into the update pass; strict > keeps first-max semantics)
template <int N, int M, int T>
__global__ __launch_bounds__(T, 2) void k_fps(const float* __restrict__ xyz,
                                              int* __restrict__ idx_out) {
    constexpr int P = N / T;
    constexpr int W = T / 64;
    int b = blockIdx.x;
    const float* X = xyz + (size_t)b * N * 3;
    int t = threadIdx.x;
    int w = t >> 6;
    __shared__ unsigned long long skey[2][W];
    __shared__ float scx[2][W], scy[2][W], scz[2][W];
    float px[P], py[P], pz[P], dmin[P];
    float c0x = X[0], c0y = X[1], c0z = X[2];
    float bv = -1.0f, bcx = 0.f, bcy = 0.f, bcz = 0.f;
    int bi = 0;
#pragma unroll
    for (int i = 0; i < P; i++) {
        int p = i * T + t;
        px[i] = X[p * 3 + 0];
        py[i] = X[p * 3 + 1];
        pz[i] = X[p * 3 + 2];
        dmin[i] = sqdist(px[i], py[i], pz[i], c0x, c0y, c0z);
        if (dmin[i] > bv) { bv = dmin[i]; bi = p; bcx = px[i]; bcy = py[i]; bcz = pz[i]; }
    }
    if (t == 0) idx_out[b * M] = 0;
    for (int j = 1; j < M; j++) {
        unsigned long long key =
            ((unsigned long long)__float_as_uint(bv) << 32) | (unsigned int)~bi;
#pragma unroll
        for (int m = 1; m < 64; m <<= 1) {
            unsigned long long ok = __shfl_xor(key, m, 64);
            if (ok > key) key = ok;
        }
        int sl = j & 1;
        int bi_w = (int)~(unsigned int)key;  // wave winner's global index
        if (t == (bi_w & (T - 1))) {          // unique owner lane of the winner
            skey[sl][w] = key;
            scx[sl][w] = bcx; scy[sl][w] = bcy; scz[sl][w] = bcz;
        }
        __syncthreads();
        unsigned long long gk = skey[sl][0];
        int w0 = 0;
#pragma unroll
        for (int u = 1; u < W; u++) {
            unsigned long long ok = skey[sl][u];
            if (ok > gk) { gk = ok; w0 = u; }
        }
        float cx = scx[sl][w0], cy = scy[sl][w0], cz = scz[sl][w0];
        if (t == 0) idx_out[b * M + j] = (int)~(unsigned int)gk;
        bv = -1.0f; bi = 0;
#pragma unroll
        for (int i = 0; i < P; i++) {
            float d = sqdist(px[i], py[i], pz[i], cx, cy, cz);
            dmin[i] = fminf(dmin[i], d);
            if (dmin[i] > bv) { bv = dmin[i]; bi = i * T + t; bcx = px[i]; bcy = py[i]; bcz = pz[i]; }
        }
        // no second barrier: next iteration writes the OTHER slot, and any
        // thread reaching iteration j+2's write has passed barrier j+1,
        // which implies all threads finished reading slot j.
    }
}

// -------------------------------------------------------------- gather ------
__global__ __launch_bounds__(256) void k_gather(const float* __restrict__ xyz_src,
                                                const int* __restrict__ idx,
                                                float* __restrict__ xyz_dst,
                                                int NS, int M) {
    int i = blockIdx.x * blockDim.x + threadIdx.x;
    if (i >= 2 * M) return;
    int b = i / M;
    int id = idx[i] & (NS - 1);
    xyz_dst[i * 3 + 0] = xyz_src[((size_t)b * NS + id) * 3 + 0];
    xyz_dst[i * 3 + 1] = xyz_src[((size_t)b * NS + id) * 3 + 1];
    xyz_dst[i * 3 + 2] = xyz_src[((size_t)b * NS + id) * 3 + 2];
}

// ------------------------------------------------------------- SetConv ------
template <int NS, int CF, int CMID, int COUT>
__global__ __launch_bounds__(128) void k_setconv(
    const float* __restrict__ X, const unsigned short* __restrict__ F,
    const float* __restrict__ C, const float* __restrict__ w1,
    const float* __restrict__ b1, const float* __restrict__ w2,
    const float* __restrict__ b2, unsigned short* __restrict__ fout,
    float r2, int M) {
    constexpr int CIN = 3 + CF;
    constexpr int K = 16;
    constexpr int M8 = CMID / 8;
    constexpr int O8 = COUT / 8;
    int q = blockIdx.x, b = blockIdx.y;
    int blk = b * M + q;
    const float* Xb = X + (size_t)b * NS * 3;
    const unsigned short* Fb = F + (size_t)b * NS * CF;
    int tid = threadIdx.x;
    __shared__ int s_n[K];
    __shared__ int s_cnt;
    __shared__ float s_h[K][CIN];
    __shared__ float s_mid[K][CMID];
    __shared__ float s_pool[2][COUT];
    float cx = C[(size_t)blk * 3 + 0], cy = C[(size_t)blk * 3 + 1], cz = C[(size_t)blk * 3 + 2];
    if (tid < 64) {
        int lane = tid;
        int cnt = 0;
        for (int base = 0; base < NS; base += 64) {
            int p = base + lane;
            float d2 = sqdist(Xb[p * 3], Xb[p * 3 + 1], Xb[p * 3 + 2], cx, cy, cz);
            bool in = (d2 <= r2);
            unsigned long long msk = __ballot(in);
            if (in) {
                int pos = cnt + __popcll(msk & ((1ull << lane) - 1ull));
                if (pos < K) s_n[pos] = p;
            }
            cnt += __popcll(msk);
            if (cnt >= K) break;
        }
        if (lane == 0) s_cnt = cnt < K ? cnt : K;
    }
    __syncthreads();
    int cnt = s_cnt;
    if (tid >= cnt && tid < K) s_n[tid] = s_n[0];  // pad (center itself always hits)
    __syncthreads();
    for (int tIdx = tid; tIdx < K * CIN; tIdx += 128) {
        int n = tIdx / CIN, c = tIdx % CIN;
        int gi = s_n[n];
        float v;
        if (c < 3) v = __fsub_rn(Xb[gi * 3 + c], (c == 0 ? cx : (c == 1 ? cy : cz)));
        else v = bf2f(Fb[(size_t)gi * CF + (c - 3)]);
        s_h[n][c] = v;
    }
    __syncthreads();
    int n = tid >> 3, sub = tid & 7;
#pragma unroll
    for (int j = 0; j < M8; j++) {
        int m = sub * M8 + j;
        float acc = b1[m];
#pragma unroll 4
        for (int c = 0; c < CIN; c++) acc = fmaf(w1[m * CIN + c], s_h[n][c], acc);
        s_mid[n][m] = fmaxf(acc, 0.f);
    }
    __syncthreads();
    float vals[O8];
#pragma unroll
    for (int j = 0; j < O8; j++) {
        int o = sub * O8 + j;
        float acc = b2[o];
#pragma unroll 4
        for (int c = 0; c < CMID; c++) acc = fmaf(w2[o * CMID + c], s_mid[n][c], acc);
        vals[j] = fmaxf(acc, 0.f);
    }
#pragma unroll
    for (int j = 0; j < O8; j++) {
        vals[j] = fmaxf(vals[j], __shfl_xor(vals[j], 8, 64));
        vals[j] = fmaxf(vals[j], __shfl_xor(vals[j], 16, 64));
        vals[j] = fmaxf(vals[j], __shfl_xor(vals[j], 32, 64));
    }
    int lw = tid & 63, wv = tid >> 6;
    if (lw < 8) {
#pragma unroll
        for (int j = 0; j < O8; j++) s_pool[wv][lw * O8 + j] = vals[j];
    }
    __syncthreads();
    if (tid < 8) {
#pragma unroll
        for (int j = 0; j < O8; j++) {
            int o = tid * O8 + j;
            fout[(size_t)blk * COUT + o] = f2bf(fmaxf(s_pool[0][o], s_pool[1][o]));
        }
    }
}

// ------------------------------------------------------------ SetUpConv -----
template <int S, int CS, int CMID, int CD, int COUT, bool TRANS>
__global__ __launch_bounds__(64) void k_upconv(
    const float* __restrict__ SX, const float* __restrict__ DX,
    const void* __restrict__ SFv, const unsigned short* __restrict__ DF,
    const float* __restrict__ w1, const float* __restrict__ b1,
    const float* __restrict__ w2, const float* __restrict__ b2,
    float* __restrict__ out, int o_off, int ND) {
    constexpr int K = 8;
    constexpr int CIN = 3 + CS;
    constexpr int CIN2 = CMID + CD;
    constexpr int M8 = CMID / 8;
    int q = blockIdx.x, b = blockIdx.y;
    int blk = b * ND + q;
    int lane = threadIdx.x;
    const float* SXb = SX + (size_t)b * S * 3;
    float qx = DX[(size_t)blk * 3], qy = DX[(size_t)blk * 3 + 1], qz = DX[(size_t)blk * 3 + 2];
    __shared__ int s_k[K];
    __shared__ float s_h[K][CIN];
    __shared__ float s_in2[CIN2];
    float bd[K];
    int bi[K];
#pragma unroll
    for (int i = 0; i < K; i++) { bd[i] = 3.0e38f; bi[i] = 0x7fffffff; }
    for (int p = lane; p < S; p += 64) {
        float d2 = sqdist(SXb[p * 3], SXb[p * 3 + 1], SXb[p * 3 + 2], qx, qy, qz);
        if (d2 < bd[K - 1] || (d2 == bd[K - 1] && p < bi[K - 1])) {
            bd[K - 1] = d2; bi[K - 1] = p;
#pragma unroll
            for (int j = K - 1; j > 0; j--) {
                bool sw = (bd[j] < bd[j - 1]) || (bd[j] == bd[j - 1] && bi[j] < bi[j - 1]);
                if (sw) {
                    float tv = bd[j]; bd[j] = bd[j - 1]; bd[j - 1] = tv;
                    int ti = bi[j]; bi[j] = bi[j - 1]; bi[j - 1] = ti;
                }
            }
        }
    }
    for (int r = 0; r < K; r++) {
        float vv = bd[0]; int vi = bi[0];
#pragma unroll
        for (int m = 1; m < 64; m <<= 1) {
            float ov = __shfl_xor(vv, m, 64);
            int oi = __shfl_xor(vi, m, 64);
            if (ov < vv || (ov == vv && oi < vi)) { vv = ov; vi = oi; }
        }
        if (lane == 0) s_k[r] = vi;
        if (vi == bi[0]) {
#pragma unroll
            for (int j = 0; j < K - 1; j++) { bd[j] = bd[j + 1]; bi[j] = bi[j + 1]; }
            bd[K - 1] = 3.0e38f; bi[K - 1] = 0x7fffffff;
        }
    }
    __syncthreads();
    for (int tIdx = lane; tIdx < K * CIN; tIdx += 64) {
        int n = tIdx / CIN, c = tIdx % CIN;
        int gi = s_k[n];
        float v;
        if (c < 3) v = __fsub_rn(SXb[gi * 3 + c], (c == 0 ? qx : (c == 1 ? qy : qz)));
        else if (TRANS) v = ((const float*)SFv)[((size_t)b * CS + (c - 3)) * S + gi];
        else v = bf2f(((const unsigned short*)SFv)[((size_t)b * S + gi) * CS + (c - 3)]);
        s_h[n][c] = v;
    }
    for (int c = lane; c < CD; c += 64) s_in2[CMID + c] = bf2f(DF[(size_t)blk * CD + c]);
    __syncthreads();
    int n = lane >> 3, sub = lane & 7;
    float vals[M8];
#pragma unroll
    for (int j = 0; j < M8; j++) {
        int m = sub * M8 + j;
        float acc = b1[m];
#pragma unroll 4
        for (int c = 0; c < CIN; c++) acc = fmaf(w1[m * CIN + c], s_h[n][c], acc);
        vals[j] = fmaxf(acc, 0.f);
    }
#pragma unroll
    for (int j = 0; j < M8; j++) {
        vals[j] = fmaxf(vals[j], __shfl_xor(vals[j], 8, 64));
        vals[j] = fmaxf(vals[j], __shfl_xor(vals[j], 16, 64));
        vals[j] = fmaxf(vals[j], __shfl_xor(vals[j], 32, 64));
    }
    if (lane < 8) {
#pragma unroll
        for (int j = 0; j < M8; j++) s_in2[lane * M8 + j] = vals[j];
    }
    __syncthreads();
    for (int o = lane; o < COUT; o += 64) {
        float acc = b2[o];
#pragma unroll 4
        for (int c = 0; c < CIN2; c++) acc = fmaf(w2[o * CIN2 + c], s_in2[c], acc);
        out[o_off + ((size_t)b * COUT + o) * ND + q] = fmaxf(acc, 0.f);
    }
}

// ------------------------------------------------------------- finalize -----
__global__ __launch_bounds__(256) void k_finalize(
    const float* __restrict__ xyz1, const float* __restrict__ xyz2,
    const float* __restrict__ xyz3, const int* __restrict__ idx1,
    const int* __restrict__ idx2, const int* __restrict__ idx3,
    float* __restrict__ out) {
    int i = blockIdx.x * blockDim.x + threadIdx.x;
    const float* xs;
    const int* is;
    int M, ox, oi, j;
    if (i < 4096) { xs = xyz1; is = idx1; M = 2048; ox = O_X1; oi = O_I1; j = i; }
    else if (i < 5120) { xs = xyz2; is = idx2; M = 512; ox = O_X2; oi = O_I2; j = i - 4096; }
    else if (i < 5376) { xs = xyz3; is = idx3; M = 128; ox = O_X3; oi = O_I3; j = i - 5120; }
    else return;
    int b = j / M, m = j % M;
    out[ox + (b * 3 + 0) * M + m] = xs[j * 3 + 0];
    out[ox + (b * 3 + 1) * M + m] = xs[j * 3 + 1];
    out[ox + (b * 3 + 2) * M + m] = xs[j * 3 + 2];
    out[oi + j] = (float)is[j];
}

// ---------------------------------------------------------------- launch ----
extern "C" void kernel_launch(void* const* d_in, const int* in_sizes, int n_in,
                              void* d_out, int out_size, void* d_ws, size_t ws_size,
                              hipStream_t stream) {
    const float* pc = (const float*)d_in[0];
    const float* feat = (const float*)d_in[1];
    const float* w0 = (const float*)d_in[2];
    const float* b0v = (const float*)d_in[3];
    const float* sc1w1 = (const float*)d_in[4];  const float* sc1b1 = (const float*)d_in[5];
    const float* sc1w2 = (const float*)d_in[6];  const float* sc1b2 = (const float*)d_in[7];
    const float* sc2w1 = (const float*)d_in[8];  const float* sc2b1 = (const float*)d_in[9];
    const float* sc2w2 = (const float*)d_in[10]; const float* sc2b2 = (const float*)d_in[11];
    const float* sc3w1 = (const float*)d_in[12]; const float* sc3b1 = (const float*)d_in[13];
    const float* sc3w2 = (const float*)d_in[14]; const float* sc3b2 = (const float*)d_in[15];
    const float* sc4w1 = (const float*)d_in[16]; const float* sc4b1 = (const float*)d_in[17];
    const float* sc4w2 = (const float*)d_in[18]; const float* sc4b2 = (const float*)d_in[19];
    const float* up4w1 = (const float*)d_in[20]; const float* up4b1 = (const float*)d_in[21];
    const float* up4w2 = (const float*)d_in[22]; const float* up4b2 = (const float*)d_in[23];
    const float* up3w1 = (const float*)d_in[24]; const float* up3b1 = (const float*)d_in[25];
    const float* up3w2 = (const float*)d_in[26]; const float* up3b2 = (const float*)d_in[27];
    const float* up2w1 = (const float*)d_in[28]; const float* up2b1 = (const float*)d_in[29];
    const float* up2w2 = (const float*)d_in[30]; const float* up2b2 = (const float*)d_in[31];
    const float* up1w1 = (const float*)d_in[32]; const float* up1b1 = (const float*)d_in[33];
    const float* up1w2 = (const float*)d_in[34]; const float* up1b2 = (const float*)d_in[35];
    float* out = (float*)d_out;

    char* ws = (char*)d_ws;
    size_t off = 0;
    auto A = [&](size_t bytes) -> char* {
        char* p = ws + off;
        off += (bytes + 255) & ~(size_t)255;
        return p;
    };
    float* xyz  = (float*)A((size_t)2 * 8192 * 3 * 4);
    int* idx1   = (int*)A((size_t)2 * 2048 * 4);
    int* idx2   = (int*)A((size_t)2 * 512 * 4);
    int* idx3   = (int*)A((size_t)2 * 128 * 4);
    int* idx4   = (int*)A((size_t)2 * 64 * 4);
    float* xyz1 = (float*)A((size_t)2 * 2048 * 3 * 4);
    float* xyz2 = (float*)A((size_t)2 * 512 * 3 * 4);
    float* xyz3 = (float*)A((size_t)2 * 128 * 3 * 4);
    float* xyz4 = (float*)A((size_t)2 * 64 * 3 * 4);
    unsigned short* f0 = (unsigned short*)A((size_t)2 * 8192 * 32 * 2);
    unsigned short* f1 = (unsigned short*)A((size_t)2 * 2048 * 64 * 2);
    unsigned short* f2 = (unsigned short*)A((size_t)2 * 512 * 128 * 2);
    unsigned short* f3 = (unsigned short*)A((size_t)2 * 128 * 192 * 2);
    unsigned short* f4 = (unsigned short*)A((size_t)2 * 64 * 192 * 2);

    k_init<<<(2 * 8192 + 255) / 256, 256, 0, stream>>>(pc, feat, w0, b0v, xyz, f0);

    // ---- down path (ws only)
    k_fps<8192, 2048, 512><<<2, 512, 0, stream>>>(xyz, idx1);
    k_gather<<<16, 256, 0, stream>>>(xyz, idx1, xyz1, 8192, 2048);
    k_setconv<8192, 32, 32, 64><<<dim3(2048, 2), 128, 0, stream>>>(
        xyz, f0, xyz1, sc1w1, sc1b1, sc1w2, sc1b2, f1, 0.25f, 2048);

    k_fps<2048, 512, 512><<<2, 512, 0, stream>>>(xyz1, idx2);
    k_gather<<<4, 256, 0, stream>>>(xyz1, idx2, xyz2, 2048, 512);
    k_setconv<2048, 64, 64, 128><<<dim3(512, 2), 128, 0, stream>>>(
        xyz1, f1, xyz2, sc2w1, sc2b1, sc2w2, sc2b2, f2, 1.0f, 512);

    k_fps<512, 128, 512><<<2, 512, 0, stream>>>(xyz2, idx3);
    k_gather<<<1, 256, 0, stream>>>(xyz2, idx3, xyz3, 512, 128);
    k_setconv<512, 128, 128, 192><<<dim3(128, 2), 128, 0, stream>>>(
        xyz2, f2, xyz3, sc3w1, sc3b1, sc3w2, sc3b2, f3, 4.0f, 128);

    k_fps<128, 64, 128><<<2, 128, 0, stream>>>(xyz3, idx4);
    k_gather<<<1, 128, 0, stream>>>(xyz3, idx4, xyz4, 128, 64);
    k_setconv<128, 192, 192, 192><<<dim3(64, 2), 128, 0, stream>>>(
        xyz3, f3, xyz4, sc4w1, sc4b1, sc4w2, sc4b2, f4, 16.0f, 64);

    // ---- up path: u-features live ONLY in their final out regions (f32)
    k_upconv<64, 192, 192, 192, 192, false><<<dim3(128, 2), 64, 0, stream>>>(
        xyz4, xyz3, f4, f3, up4w1, up4b1, up4w2, up4b2, out, O_U3, 128);
    k_upconv<128, 192, 128, 128, 128, true><<<dim3(512, 2), 64, 0, stream>>>(
        xyz3, xyz2, out + O_U3, f2, up3w1, up3b1, up3w2, up3b2, out, O_U2, 512);
    k_upconv<512, 128, 64, 64, 64, true><<<dim3(2048, 2), 64, 0, stream>>>(
        xyz2, xyz1, out + O_U2, f1, up2w1, up2b1, up2w2, up2b2, out, O_U1, 2048);
    k_upconv<2048, 64, 32, 32, 32, true><<<dim3(8192, 2), 64, 0, stream>>>(
        xyz1, xyz, out + O_U1, f0, up1w1, up1b1, up1w2, up1b2, out, O_U0, 8192);

    // ---- x/i outputs written last
    k_finalize<<<(5376 + 255) / 256, 256, 0, stream>>>(
        xyz1, xyz2, xyz3, idx1, idx2, idx3, out);
}

// Round 6
// 4460.180 us; speedup vs baseline: 1.3794x; 1.1247x over previous
//
#include <hip/hip_runtime.h>
#include <hip/hip_bf16.h>
#include <cstdint>

#define DEV __device__ __forceinline__

// Exact per-op-rounded squared distance, matching numpy's ((dx^2+dy^2)+dz^2)
// with no FMA contraction. All index decisions (FPS/ball/kNN) depend on this
// being bit-identical to the f32 reference.
DEV float sqdist(float ax, float ay, float az, float bx, float by, float bz) {
    float dx = __fsub_rn(ax, bx), dy = __fsub_rn(ay, by), dz = __fsub_rn(az, bz);
    return __fadd_rn(__fadd_rn(__fmul_rn(dx, dx), __fmul_rn(dy, dy)), __fmul_rn(dz, dz));
}

DEV unsigned short f2bf(float f) {  // RNE f32 -> bf16 (ws feature storage only)
    unsigned int u = __float_as_uint(f);
    u += 0x7fffu + ((u >> 16) & 1u);
    return (unsigned short)(u >> 16);
}

DEV float bf2f(unsigned short u) { return __uint_as_float(((unsigned int)u) << 16); }

// Output offsets (f32 elements) in return order.
enum : int {
    O_X1 = 0, O_X2 = 12288, O_X3 = 15360,
    O_I1 = 16128, O_I2 = 20224, O_I3 = 21248,
    O_U0 = 21504, O_U1 = 545792, O_U2 = 807936, O_U3 = 939008
};

// ---------------------------------------------------------------- init ------
__global__ __launch_bounds__(256) void k_init(const float* __restrict__ pc,
                                              const float* __restrict__ feat,
                                              const float* __restrict__ w0,
                                              const float* __restrict__ b0,
                                              float* __restrict__ xyz,
                                              unsigned short* __restrict__ f0) {
    const int N = 8192;
    int i = blockIdx.x * blockDim.x + threadIdx.x;
    if (i >= 2 * N) return;
    int b = i / N, n = i % N;
    float fx0 = feat[(b * 3 + 0) * N + n];
    float fx1 = feat[(b * 3 + 1) * N + n];
    float fx2 = feat[(b * 3 + 2) * N + n];
    xyz[i * 3 + 0] = pc[(b * 3 + 0) * N + n];
    xyz[i * 3 + 1] = pc[(b * 3 + 1) * N + n];
    xyz[i * 3 + 2] = pc[(b * 3 + 2) * N + n];
#pragma unroll
    for (int o = 0; o < 32; o++) {
        float acc = b0[o];
        acc = fmaf(w0[o * 3 + 0], fx0, acc);
        acc = fmaf(w0[o * 3 + 1], fx1, acc);
        acc = fmaf(w0[o * 3 + 2], fx2, acc);
        f0[(size_t)i * 32 + o] = f2bf(fmaxf(acc, 0.f));
    }
}

// ----------------------------------------------------------------- FPS ------
// One block per batch. Points + dmin in registers; xyz ALSO mirrored in LDS
// (96KB max at N=8192; MI355X has 160KB/CU) so the winner's coords are a
// broadcast LDS read, not a register-tracked select chain.
// Per iteration (ONE barrier):
//   tree fmax over P (bit-exact reassociation) -> equality scan -> index-min
//   tree -> packed u64 key (dist_bits<<32 | ~idx) -> wave butterfly (max key
//   == max dist, min index: numpy first-max) -> lane0 writes slot ->
//   barrier -> serial W-slot reduce -> coords from LDS -> dmin update.
template <int N, int M, int T>
__global__ __launch_bounds__(T, 1) void k_fps(const float* __restrict__ xyz,
                                              int* __restrict__ idx_out) {
    constexpr int P = N / T;
    constexpr int W = T / 64;
    int b = blockIdx.x;
    const float* X = xyz + (size_t)b * N * 3;
    int t = threadIdx.x;
    int w = t >> 6;
    __shared__ float sx[N], sy[N], sz[N];
    __shared__ unsigned long long skey[2][W];
    float px[P], py[P], pz[P], dmin[P];
    float c0x = X[0], c0y = X[1], c0z = X[2];
#pragma unroll
    for (int i = 0; i < P; i++) {
        int p = i * T + t;
        px[i] = X[p * 3 + 0];
        py[i] = X[p * 3 + 1];
        pz[i] = X[p * 3 + 2];
        sx[p] = px[i]; sy[p] = py[i]; sz[p] = pz[i];
        dmin[i] = sqdist(px[i], py[i], pz[i], c0x, c0y, c0z);
    }
    if (t == 0) idx_out[b * M] = 0;
    // first LDS read of sx/sy/sz happens only after iteration 1's barrier.
    for (int j = 1; j < M; j++) {
        // local max value: explicit tree (independent ops, depth log2 P)
        float mv[P];
#pragma unroll
        for (int i = 0; i < P; i++) mv[i] = dmin[i];
#pragma unroll
        for (int s = P / 2; s >= 1; s >>= 1)
#pragma unroll
            for (int i = 0; i < s; i++) mv[i] = fmaxf(mv[i], mv[i + s]);
        float bv = mv[0];
        // first (=min) local index achieving bv: equality scan + min tree
        int ii[P];
#pragma unroll
        for (int i = 0; i < P; i++) ii[i] = (dmin[i] == bv) ? (i * T + t) : 0x7fffffff;
#pragma unroll
        for (int s = P / 2; s >= 1; s >>= 1)
#pragma unroll
            for (int i = 0; i < s; i++) ii[i] = min(ii[i], ii[i + s]);
        unsigned long long key =
            ((unsigned long long)__float_as_uint(bv) << 32) | (unsigned int)~ii[0];
#pragma unroll
        for (int m = 1; m < 64; m <<= 1) {
            unsigned long long ok = __shfl_xor(key, m, 64);
            key = ok > key ? ok : key;
        }
        int sl = j & 1;
        if ((t & 63) == 0) skey[sl][w] = key;
        __syncthreads();
        unsigned long long gk = skey[sl][0];
#pragma unroll
        for (int u = 1; u < W; u++) {
            unsigned long long ok = skey[sl][u];
            gk = ok > gk ? ok : gk;
        }
        int gi = (int)~(unsigned int)gk;
        if (t == 0) idx_out[b * M + j] = gi;
        float cx = sx[gi], cy = sy[gi], cz = sz[gi];  // broadcast, conflict-free
#pragma unroll
        for (int i = 0; i < P; i++)
            dmin[i] = fminf(dmin[i], sqdist(px[i], py[i], pz[i], cx, cy, cz));
        // no second barrier: iteration j+1 writes the OTHER slot parity, and
        // reaching that write implies passing barrier j, which implies every
        // thread finished reading slot parity j-1 (== j+1's parity).
    }
}

// -------------------------------------------------------------- gather ------
__global__ __launch_bounds__(256) void k_gather(const float* __restrict__ xyz_src,
                                                const int* __restrict__ idx,
                                                float* __restrict__ xyz_dst,
                                                int NS, int M) {
    int i = blockIdx.x * blockDim.x + threadIdx.x;
    if (i >= 2 * M) return;
    int b = i / M;
    int id = idx[i] & (NS - 1);
    xyz_dst[i * 3 + 0] = xyz_src[((size_t)b * NS + id) * 3 + 0];
    xyz_dst[i * 3 + 1] = xyz_src[((size_t)b * NS + id) * 3 + 1];
    xyz_dst[i * 3 + 2] = xyz_src[((size_t)b * NS + id) * 3 + 2];
}

// ------------------------------------------------------------- SetConv ------
template <int NS, int CF, int CMID, int COUT>
__global__ __launch_bounds__(128) void k_setconv(
    const float* __restrict__ X, const unsigned short* __restrict__ F,
    const float* __restrict__ C, const float* __restrict__ w1,
    const float* __restrict__ b1, const float* __restrict__ w2,
    const float* __restrict__ b2, unsigned short* __restrict__ fout,
    float r2, int M) {
    constexpr int CIN = 3 + CF;
    constexpr int K = 16;
    constexpr int M8 = CMID / 8;
    constexpr int O8 = COUT / 8;
    int q = blockIdx.x, b = blockIdx.y;
    int blk = b * M + q;
    const float* Xb = X + (size_t)b * NS * 3;
    const unsigned short* Fb = F + (size_t)b * NS * CF;
    int tid = threadIdx.x;
    __shared__ int s_n[K];
    __shared__ int s_cnt;
    __shared__ float s_h[K][CIN];
    __shared__ float s_mid[K][CMID];
    __shared__ float s_pool[2][COUT];
    float cx = C[(size_t)blk * 3 + 0], cy = C[(size_t)blk * 3 + 1], cz = C[(size_t)blk * 3 + 2];
    if (tid < 64) {
        int lane = tid;
        int cnt = 0;
        for (int base = 0; base < NS; base += 64) {
            int p = base + lane;
            float d2 = sqdist(Xb[p * 3], Xb[p * 3 + 1], Xb[p * 3 + 2], cx, cy, cz);
            bool in = (d2 <= r2);
            unsigned long long msk = __ballot(in);
            if (in) {
                int pos = cnt + __popcll(msk & ((1ull << lane) - 1ull));
                if (pos < K) s_n[pos] = p;
            }
            cnt += __popcll(msk);
            if (cnt >= K) break;
        }
        if (lane == 0) s_cnt = cnt < K ? cnt : K;
    }
    __syncthreads();
    int cnt = s_cnt;
    if (tid >= cnt && tid < K) s_n[tid] = s_n[0];  // pad (center itself always hits)
    __syncthreads();
    for (int tIdx = tid; tIdx < K * CIN; tIdx += 128) {
        int n = tIdx / CIN, c = tIdx % CIN;
        int gi = s_n[n];
        float v;
        if (c < 3) v = __fsub_rn(Xb[gi * 3 + c], (c == 0 ? cx : (c == 1 ? cy : cz)));
        else v = bf2f(Fb[(size_t)gi * CF + (c - 3)]);
        s_h[n][c] = v;
    }
    __syncthreads();
    int n = tid >> 3, sub = tid & 7;
#pragma unroll
    for (int j = 0; j < M8; j++) {
        int m = sub * M8 + j;
        float acc = b1[m];
#pragma unroll 4
        for (int c = 0; c < CIN; c++) acc = fmaf(w1[m * CIN + c], s_h[n][c], acc);
        s_mid[n][m] = fmaxf(acc, 0.f);
    }
    __syncthreads();
    float vals[O8];
#pragma unroll
    for (int j = 0; j < O8; j++) {
        int o = sub * O8 + j;
        float acc = b2[o];
#pragma unroll 4
        for (int c = 0; c < CMID; c++) acc = fmaf(w2[o * CMID + c], s_mid[n][c], acc);
        vals[j] = fmaxf(acc, 0.f);
    }
#pragma unroll
    for (int j = 0; j < O8; j++) {
        vals[j] = fmaxf(vals[j], __shfl_xor(vals[j], 8, 64));
        vals[j] = fmaxf(vals[j], __shfl_xor(vals[j], 16, 64));
        vals[j] = fmaxf(vals[j], __shfl_xor(vals[j], 32, 64));
    }
    int lw = tid & 63, wv = tid >> 6;
    if (lw < 8) {
#pragma unroll
        for (int j = 0; j < O8; j++) s_pool[wv][lw * O8 + j] = vals[j];
    }
    __syncthreads();
    if (tid < 8) {
#pragma unroll
        for (int j = 0; j < O8; j++) {
            int o = tid * O8 + j;
            fout[(size_t)blk * COUT + o] = f2bf(fmaxf(s_pool[0][o], s_pool[1][o]));
        }
    }
}

// ------------------------------------------------------------ SetUpConv -----
template <int S, int CS, int CMID, int CD, int COUT, bool TRANS>
__global__ __launch_bounds__(64) void k_upconv(
    const float* __restrict__ SX, const float* __restrict__ DX,
    const void* __restrict__ SFv, const unsigned short* __restrict__ DF,
    const float* __restrict__ w1, const float* __restrict__ b1,
    const float* __restrict__ w2, const float* __restrict__ b2,
    float* __restrict__ out, int o_off, int ND) {
    constexpr int K = 8;
    constexpr int CIN = 3 + CS;
    constexpr int CIN2 = CMID + CD;
    constexpr int M8 = CMID / 8;
    int q = blockIdx.x, b = blockIdx.y;
    int blk = b * ND + q;
    int lane = threadIdx.x;
    const float* SXb = SX + (size_t)b * S * 3;
    float qx = DX[(size_t)blk * 3], qy = DX[(size_t)blk * 3 + 1], qz = DX[(size_t)blk * 3 + 2];
    __shared__ int s_k[K];
    __shared__ float s_h[K][CIN];
    __shared__ float s_in2[CIN2];
    float bd[K];
    int bi[K];
#pragma unroll
    for (int i = 0; i < K; i++) { bd[i] = 3.0e38f; bi[i] = 0x7fffffff; }
    for (int p = lane; p < S; p += 64) {
        float d2 = sqdist(SXb[p * 3], SXb[p * 3 + 1], SXb[p * 3 + 2], qx, qy, qz);
        if (d2 < bd[K - 1] || (d2 == bd[K - 1] && p < bi[K - 1])) {
            bd[K - 1] = d2; bi[K - 1] = p;
#pragma unroll
            for (int j = K - 1; j > 0; j--) {
                bool sw = (bd[j] < bd[j - 1]) || (bd[j] == bd[j - 1] && bi[j] < bi[j - 1]);
                if (sw) {
                    float tv = bd[j]; bd[j] = bd[j - 1]; bd[j - 1] = tv;
                    int ti = bi[j]; bi[j] = bi[j - 1]; bi[j - 1] = ti;
                }
            }
        }
    }
    for (int r = 0; r < K; r++) {
        float vv = bd[0]; int vi = bi[0];
#pragma unroll
        for (int m = 1; m < 64; m <<= 1) {
            float ov = __shfl_xor(vv, m, 64);
            int oi = __shfl_xor(vi, m, 64);
            if (ov < vv || (ov == vv && oi < vi)) { vv = ov; vi = oi; }
        }
        if (lane == 0) s_k[r] = vi;
        if (vi == bi[0]) {
#pragma unroll
            for (int j = 0; j < K - 1; j++) { bd[j] = bd[j + 1]; bi[j] = bi[j + 1]; }
            bd[K - 1] = 3.0e38f; bi[K - 1] = 0x7fffffff;
        }
    }
    __syncthreads();
    for (int tIdx = lane; tIdx < K * CIN; tIdx += 64) {
        int n = tIdx / CIN, c = tIdx % CIN;
        int gi = s_k[n];
        float v;
        if (c < 3) v = __fsub_rn(SXb[gi * 3 + c], (c == 0 ? qx : (c == 1 ? qy : qz)));
        else if (TRANS) v = ((const float*)SFv)[((size_t)b * CS + (c - 3)) * S + gi];
        else v = bf2f(((const unsigned short*)SFv)[((size_t)b * S + gi) * CS + (c - 3)]);
        s_h[n][c] = v;
    }
    for (int c = lane; c < CD; c += 64) s_in2[CMID + c] = bf2f(DF[(size_t)blk * CD + c]);
    __syncthreads();
    int n = lane >> 3, sub = lane & 7;
    float vals[M8];
#pragma unroll
    for (int j = 0; j < M8; j++) {
        int m = sub * M8 + j;
        float acc = b1[m];
#pragma unroll 4
        for (int c = 0; c < CIN; c++) acc = fmaf(w1[m * CIN + c], s_h[n][c], acc);
        vals[j] = fmaxf(acc, 0.f);
    }
#pragma unroll
    for (int j = 0; j < M8; j++) {
        vals[j] = fmaxf(vals[j], __shfl_xor(vals[j], 8, 64));
        vals[j] = fmaxf(vals[j], __shfl_xor(vals[j], 16, 64));
        vals[j] = fmaxf(vals[j], __shfl_xor(vals[j], 32, 64));
    }
    if (lane < 8) {
#pragma unroll
        for (int j = 0; j < M8; j++) s_in2[lane * M8 + j] = vals[j];
    }
    __syncthreads();
    for (int o = lane; o < COUT; o += 64) {
        float acc = b2[o];
#pragma unroll 4
        for (int c = 0; c < CIN2; c++) acc = fmaf(w2[o * CIN2 + c], s_in2[c], acc);
        out[o_off + ((size_t)b * COUT + o) * ND + q] = fmaxf(acc, 0.f);
    }
}

// ------------------------------------------------------------- finalize -----
__global__ __launch_bounds__(256) void k_finalize(
    const float* __restrict__ xyz1, const float* __restrict__ xyz2,
    const float* __restrict__ xyz3, const int* __restrict__ idx1,
    const int* __restrict__ idx2, const int* __restrict__ idx3,
    float* __restrict__ out) {
    int i = blockIdx.x * blockDim.x + threadIdx.x;
    const float* xs;
    const int* is;
    int M, ox, oi, j;
    if (i < 4096) { xs = xyz1; is = idx1; M = 2048; ox = O_X1; oi = O_I1; j = i; }
    else if (i < 5120) { xs = xyz2; is = idx2; M = 512; ox = O_X2; oi = O_I2; j = i - 4096; }
    else if (i < 5376) { xs = xyz3; is = idx3; M = 128; ox = O_X3; oi = O_I3; j = i - 5120; }
    else return;
    int b = j / M, m = j % M;
    out[ox + (b * 3 + 0) * M + m] = xs[j * 3 + 0];
    out[ox + (b * 3 + 1) * M + m] = xs[j * 3 + 1];
    out[ox + (b * 3 + 2) * M + m] = xs[j * 3 + 2];
    out[oi + j] = (float)is[j];
}

// ---------------------------------------------------------------- launch ----
extern "C" void kernel_launch(void* const* d_in, const int* in_sizes, int n_in,
                              void* d_out, int out_size, void* d_ws, size_t ws_size,
                              hipStream_t stream) {
    const float* pc = (const float*)d_in[0];
    const float* feat = (const float*)d_in[1];
    const float* w0 = (const float*)d_in[2];
    const float* b0v = (const float*)d_in[3];
    const float* sc1w1 = (const float*)d_in[4];  const float* sc1b1 = (const float*)d_in[5];
    const float* sc1w2 = (const float*)d_in[6];  const float* sc1b2 = (const float*)d_in[7];
    const float* sc2w1 = (const float*)d_in[8];  const float* sc2b1 = (const float*)d_in[9];
    const float* sc2w2 = (const float*)d_in[10]; const float* sc2b2 = (const float*)d_in[11];
    const float* sc3w1 = (const float*)d_in[12]; const float* sc3b1 = (const float*)d_in[13];
    const float* sc3w2 = (const float*)d_in[14]; const float* sc3b2 = (const float*)d_in[15];
    const float* sc4w1 = (const float*)d_in[16]; const float* sc4b1 = (const float*)d_in[17];
    const float* sc4w2 = (const float*)d_in[18]; const float* sc4b2 = (const float*)d_in[19];
    const float* up4w1 = (const float*)d_in[20]; const float* up4b1 = (const float*)d_in[21];
    const float* up4w2 = (const float*)d_in[22]; const float* up4b2 = (const float*)d_in[23];
    const float* up3w1 = (const float*)d_in[24]; const float* up3b1 = (const float*)d_in[25];
    const float* up3w2 = (const float*)d_in[26]; const float* up3b2 = (const float*)d_in[27];
    const float* up2w1 = (const float*)d_in[28]; const float* up2b1 = (const float*)d_in[29];
    const float* up2w2 = (const float*)d_in[30]; const float* up2b2 = (const float*)d_in[31];
    const float* up1w1 = (const float*)d_in[32]; const float* up1b1 = (const float*)d_in[33];
    const float* up1w2 = (const float*)d_in[34]; const float* up1b2 = (const float*)d_in[35];
    float* out = (float*)d_out;

    char* ws = (char*)d_ws;
    size_t off = 0;
    auto A = [&](size_t bytes) -> char* {
        char* p = ws + off;
        off += (bytes + 255) & ~(size_t)255;
        return p;
    };
    float* xyz  = (float*)A((size_t)2 * 8192 * 3 * 4);
    int* idx1   = (int*)A((size_t)2 * 2048 * 4);
    int* idx2   = (int*)A((size_t)2 * 512 * 4);
    int* idx3   = (int*)A((size_t)2 * 128 * 4);
    int* idx4   = (int*)A((size_t)2 * 64 * 4);
    float* xyz1 = (float*)A((size_t)2 * 2048 * 3 * 4);
    float* xyz2 = (float*)A((size_t)2 * 512 * 3 * 4);
    float* xyz3 = (float*)A((size_t)2 * 128 * 3 * 4);
    float* xyz4 = (float*)A((size_t)2 * 64 * 3 * 4);
    unsigned short* f0 = (unsigned short*)A((size_t)2 * 8192 * 32 * 2);
    unsigned short* f1 = (unsigned short*)A((size_t)2 * 2048 * 64 * 2);
    unsigned short* f2 = (unsigned short*)A((size_t)2 * 512 * 128 * 2);
    unsigned short* f3 = (unsigned short*)A((size_t)2 * 128 * 192 * 2);
    unsigned short* f4 = (unsigned short*)A((size_t)2 * 64 * 192 * 2);

    k_init<<<(2 * 8192 + 255) / 256, 256, 0, stream>>>(pc, feat, w0, b0v, xyz, f0);

    // ---- down path (ws only)
    k_fps<8192, 2048, 512><<<2, 512, 0, stream>>>(xyz, idx1);
    k_gather<<<16, 256, 0, stream>>>(xyz, idx1, xyz1, 8192, 2048);
    k_setconv<8192, 32, 32, 64><<<dim3(2048, 2), 128, 0, stream>>>(
        xyz, f0, xyz1, sc1w1, sc1b1, sc1w2, sc1b2, f1, 0.25f, 2048);

    k_fps<2048, 512, 512><<<2, 512, 0, stream>>>(xyz1, idx2);
    k_gather<<<4, 256, 0, stream>>>(xyz1, idx2, xyz2, 2048, 512);
    k_setconv<2048, 64, 64, 128><<<dim3(512, 2), 128, 0, stream>>>(
        xyz1, f1, xyz2, sc2w1, sc2b1, sc2w2, sc2b2, f2, 1.0f, 512);

    k_fps<512, 128, 256><<<2, 256, 0, stream>>>(xyz2, idx3);
    k_gather<<<1, 256, 0, stream>>>(xyz2, idx3, xyz3, 512, 128);
    k_setconv<512, 128, 128, 192><<<dim3(128, 2), 128, 0, stream>>>(
        xyz2, f2, xyz3, sc3w1, sc3b1, sc3w2, sc3b2, f3, 4.0f, 128);

    k_fps<128, 64, 128><<<2, 128, 0, stream>>>(xyz3, idx4);
    k_gather<<<1, 128, 0, stream>>>(xyz3, idx4, xyz4, 128, 64);
    k_setconv<128, 192, 192, 192><<<dim3(64, 2), 128, 0, stream>>>(
        xyz3, f3, xyz4, sc4w1, sc4b1, sc4w2, sc4b2, f4, 16.0f, 64);

    // ---- up path: u-features live ONLY in their final out regions (f32)
    k_upconv<64, 192, 192, 192, 192, false><<<dim3(128, 2), 64, 0, stream>>>(
        xyz4, xyz3, f4, f3, up4w1, up4b1, up4w2, up4b2, out, O_U3, 128);
    k_upconv<128, 192, 128, 128, 128, true><<<dim3(512, 2), 64, 0, stream>>>(
        xyz3, xyz2, out + O_U3, f2, up3w1, up3b1, up3w2, up3b2, out, O_U2, 512);
    k_upconv<512, 128, 64, 64, 64, true><<<dim3(2048, 2), 64, 0, stream>>>(
        xyz2, xyz1, out + O_U2, f1, up2w1, up2b1, up2w2, up2b2, out, O_U1, 2048);
    k_upconv<2048, 64, 32, 32, 32, true><<<dim3(8192, 2), 64, 0, stream>>>(
        xyz1, xyz, out + O_U1, f0, up1w1, up1b1, up1w2, up1b2, out, O_U0, 8192);

    // ---- x/i outputs written last
    k_finalize<<<(5376 + 255) / 256, 256, 0, stream>>>(
        xyz1, xyz2, xyz3, idx1, idx2, idx3, out);
}